// Round 4
// baseline (351.991 us; speedup 1.0000x reference)
//
#include <hip/hip_runtime.h>
#include <hip/hip_bf16.h>

#define B_ROWS 65536
#define NA 128
#define D_OUT 1024
#define VBS 128
#define NCHUNK (B_ROWS / VBS)   // 512

typedef __attribute__((ext_vector_type(8))) short bf16x8s;
typedef __attribute__((ext_vector_type(4))) float f32x4;
typedef __attribute__((ext_vector_type(4))) unsigned short u16x4;
typedef __attribute__((ext_vector_type(8))) unsigned short u16x8;

static __device__ __forceinline__ short f2bf(float f) {
    unsigned u = __builtin_bit_cast(unsigned, f);
    u = u + 0x7FFFu + ((u >> 16) & 1u);   // round-to-nearest-even to bf16
    return (short)(u >> 16);
}
static __device__ __forceinline__ float bf2f(unsigned short h) {
    unsigned u = ((unsigned)h) << 16;
    return __builtin_bit_cast(float, u);
}

// One block per virtual batch (chunk): 128 threads, one per feature.
__global__ void gbn_stats_kernel(const float* __restrict__ a,
                                 const float* __restrict__ gamma,
                                 const float* __restrict__ beta,
                                 float* __restrict__ ss) {
    int c = blockIdx.x;
    int j = threadIdx.x;            // feature 0..127
    const float* p = a + (size_t)c * (VBS * NA) + j;
    float s = 0.f, s2 = 0.f;
#pragma unroll 8
    for (int r = 0; r < VBS; ++r) {
        float v = p[r * NA];
        s += v; s2 += v * v;
    }
    float mean = s * (1.f / VBS);
    float var  = fmaxf(s2 * (1.f / VBS) - mean * mean, 0.f);   // biased var
    float sc = gamma[j] * rsqrtf(var + 1e-5f);
    float sh = beta[j] - mean * sc;
    float2* o = (float2*)ss + (c * NA + j);
    *o = make_float2(sc, sh);
}

__global__ void wcast_kernel(const float* __restrict__ W,
                             unsigned short* __restrict__ Wb, int n) {
    int i = blockIdx.x * blockDim.x + threadIdx.x;
    if (i < n) Wb[i] = (unsigned short)f2bf(W[i]);
}

// ===================== split path: kernel A (GEMM -> y bf16) =====================
// One block per 16 rows; wave w owns cols [w*256, +256). Swapped-operand MFMA:
// thread (g,q) holds y[r0+q][w*256+nf*16+4g+r]. Epilogue: *prior, store bf16 y.
__global__ __launch_bounds__(256, 4) void gemm_kernel(
    const float* __restrict__ a,
    const float* __restrict__ prior,
    const float* __restrict__ ss,
    const unsigned short* __restrict__ Wb,
    unsigned short* __restrict__ y) {

    const int tid  = threadIdx.x;
    const int wave = tid >> 6;
    const int lane = tid & 63;
    const int g    = lane >> 4;
    const int q    = lane & 15;

    const int r0    = blockIdx.x * 16;
    const int chunk = r0 >> 7;

    f32x4 acc[16];
#pragma unroll
    for (int i = 0; i < 16; ++i) acc[i] = (f32x4){0.f, 0.f, 0.f, 0.f};

    const float* ssb = ss + (size_t)chunk * NA * 2;

#pragma unroll
    for (int ks = 0; ks < 4; ++ks) {
        const int k0 = ks * 32 + g * 8;
        const float4* ap = (const float4*)(a + (size_t)(r0 + q) * NA + k0);
        float4 v0 = ap[0], v1 = ap[1];
        const float4* sp = (const float4*)(ssb + k0 * 2);
        float4 s0 = sp[0], s1 = sp[1], s2 = sp[2], s3 = sp[3];
        bf16x8s af;
        af[0] = f2bf(v0.x * s0.x + s0.y);
        af[1] = f2bf(v0.y * s0.z + s0.w);
        af[2] = f2bf(v0.z * s1.x + s1.y);
        af[3] = f2bf(v0.w * s1.z + s1.w);
        af[4] = f2bf(v1.x * s2.x + s2.y);
        af[5] = f2bf(v1.y * s2.z + s2.w);
        af[6] = f2bf(v1.z * s3.x + s3.y);
        af[7] = f2bf(v1.w * s3.z + s3.w);

        const unsigned short* wb = Wb + (size_t)(wave * 256 + q) * NA + k0;
#pragma unroll
        for (int nf = 0; nf < 16; ++nf) {
            bf16x8s bf = *(const bf16x8s*)(wb + (size_t)nf * 16 * NA);
            acc[nf] = __builtin_amdgcn_mfma_f32_16x16x32_bf16(bf, af, acc[nf], 0, 0, 0);
        }
    }

    // *prior then store y (bf16) straight from accumulator layout
    const float* pb = prior + (size_t)(r0 + q) * D_OUT + wave * 256 + 4 * g;
    unsigned short* yb = y + (size_t)(r0 + q) * D_OUT + wave * 256 + 4 * g;
#pragma unroll
    for (int nf = 0; nf < 16; ++nf) {
        float4 p = *(const float4*)(pb + nf * 16);
        u16x4 h;
        h[0] = (unsigned short)f2bf(acc[nf][0] * p.x);
        h[1] = (unsigned short)f2bf(acc[nf][1] * p.y);
        h[2] = (unsigned short)f2bf(acc[nf][2] * p.z);
        h[3] = (unsigned short)f2bf(acc[nf][3] * p.w);
        *(u16x4*)(yb + nf * 16) = h;
    }
}

// ===================== split path: kernel B (sparsemax) =====================
// One row per wave, 4 waves/block, no LDS, ~40 VGPR -> near-full occupancy.
__global__ __launch_bounds__(256, 8) void sparsemax_kernel(
    const unsigned short* __restrict__ y,
    float* __restrict__ out) {

    const int lane = threadIdx.x & 63;
    const int row  = blockIdx.x * 4 + (threadIdx.x >> 6);

    const u16x8* yr = (const u16x8*)(y + (size_t)row * D_OUT);
    u16x8 h0 = yr[lane];        // cols lane*8 .. +8
    u16x8 h1 = yr[64 + lane];   // cols 512 + lane*8 .. +8

    float v[16];
#pragma unroll
    for (int i = 0; i < 8; ++i) {
        v[i]     = bf2f(h0[i]);
        v[8 + i] = bf2f(h1[i]);
    }

    // iteration 1 hoisted: tau = (sum_all - 1)/1024
    float s = 0.f;
#pragma unroll
    for (int e = 0; e < 16; ++e) s += v[e];
#pragma unroll
    for (int m = 1; m < 64; m <<= 1) s += __shfl_xor(s, m);
    float tau = (s - 1.f) * (1.f / 1024.f);
    float cprev = 1024.f;

    for (int it = 0; it < 32; ++it) {
        s = 0.f; float c = 0.f;
#pragma unroll
        for (int e = 0; e < 16; ++e) {
            float x = v[e];
            bool mk = x > tau;
            s += mk ? x : 0.f;
            c += mk ? 1.f : 0.f;
        }
#pragma unroll
        for (int m = 1; m < 64; m <<= 1) {
            s += __shfl_xor(s, m);
            c += __shfl_xor(c, m);
        }
        tau = (s - 1.f) / c;
        if (c == cprev) break;
        cprev = c;
    }

    float* ob = out + (size_t)row * D_OUT;
    float4 o;
    o.x = fmaxf(v[0] + tau, 0.f);  o.y = fmaxf(v[1] + tau, 0.f);
    o.z = fmaxf(v[2] + tau, 0.f);  o.w = fmaxf(v[3] + tau, 0.f);
    *(float4*)(ob + lane * 8) = o;
    o.x = fmaxf(v[4] + tau, 0.f);  o.y = fmaxf(v[5] + tau, 0.f);
    o.z = fmaxf(v[6] + tau, 0.f);  o.w = fmaxf(v[7] + tau, 0.f);
    *(float4*)(ob + lane * 8 + 4) = o;
    o.x = fmaxf(v[8] + tau, 0.f);  o.y = fmaxf(v[9] + tau, 0.f);
    o.z = fmaxf(v[10] + tau, 0.f); o.w = fmaxf(v[11] + tau, 0.f);
    *(float4*)(ob + 512 + lane * 8) = o;
    o.x = fmaxf(v[12] + tau, 0.f); o.y = fmaxf(v[13] + tau, 0.f);
    o.z = fmaxf(v[14] + tau, 0.f); o.w = fmaxf(v[15] + tau, 0.f);
    *(float4*)(ob + 512 + lane * 8 + 4) = o;
}

// ===================== fallback: R3 fused kernel (if ws too small) =====================
__global__ __launch_bounds__(256, 4) void fused_kernel(
    const float* __restrict__ a,
    const float* __restrict__ prior,
    const float* __restrict__ ss,
    const unsigned short* __restrict__ Wb,
    float* __restrict__ out) {

    const int tid  = threadIdx.x;
    const int wave = tid >> 6;
    const int lane = tid & 63;
    const int g    = lane >> 4;
    const int q    = lane & 15;

    const int r0    = blockIdx.x * 16;
    const int chunk = r0 >> 7;

    f32x4 acc[16];
#pragma unroll
    for (int i = 0; i < 16; ++i) acc[i] = (f32x4){0.f, 0.f, 0.f, 0.f};

    const float* ssb = ss + (size_t)chunk * NA * 2;

#pragma unroll
    for (int ks = 0; ks < 4; ++ks) {
        const int k0 = ks * 32 + g * 8;
        const float4* ap = (const float4*)(a + (size_t)(r0 + q) * NA + k0);
        float4 v0 = ap[0], v1 = ap[1];
        const float4* sp = (const float4*)(ssb + k0 * 2);
        float4 s0 = sp[0], s1 = sp[1], s2 = sp[2], s3 = sp[3];
        bf16x8s af;
        af[0] = f2bf(v0.x * s0.x + s0.y);
        af[1] = f2bf(v0.y * s0.z + s0.w);
        af[2] = f2bf(v0.z * s1.x + s1.y);
        af[3] = f2bf(v0.w * s1.z + s1.w);
        af[4] = f2bf(v1.x * s2.x + s2.y);
        af[5] = f2bf(v1.y * s2.z + s2.w);
        af[6] = f2bf(v1.z * s3.x + s3.y);
        af[7] = f2bf(v1.w * s3.z + s3.w);

        const unsigned short* wb = Wb + (size_t)(wave * 256 + q) * NA + k0;
#pragma unroll
        for (int nf = 0; nf < 16; ++nf) {
            bf16x8s bf = *(const bf16x8s*)(wb + (size_t)nf * 16 * NA);
            acc[nf] = __builtin_amdgcn_mfma_f32_16x16x32_bf16(bf, af, acc[nf], 0, 0, 0);
        }
    }

    {
        const float* pb = prior + (size_t)(r0 + q) * D_OUT + wave * 256 + 4 * g;
#pragma unroll
        for (int nf = 0; nf < 16; ++nf) {
            float4 p = *(const float4*)(pb + nf * 16);
            acc[nf][0] *= p.x; acc[nf][1] *= p.y;
            acc[nf][2] *= p.z; acc[nf][3] *= p.w;
        }
    }

    __shared__ unsigned short ls[16][1032];
#pragma unroll
    for (int nf = 0; nf < 16; ++nf) {
        u16x4 h;
        h[0] = (unsigned short)f2bf(acc[nf][0]);
        h[1] = (unsigned short)f2bf(acc[nf][1]);
        h[2] = (unsigned short)f2bf(acc[nf][2]);
        h[3] = (unsigned short)f2bf(acc[nf][3]);
        *(u16x4*)&ls[q][wave * 256 + nf * 16 + 4 * g] = h;
    }
    __syncthreads();

#pragma unroll 1
    for (int rr = 0; rr < 4; ++rr) {
        const int row = wave * 4 + rr;
        float va[16];
#pragma unroll
        for (int j = 0; j < 4; ++j) {
            u16x4 hv = *(const u16x4*)&ls[row][j * 256 + lane * 4];
            va[j * 4 + 0] = bf2f(hv[0]);
            va[j * 4 + 1] = bf2f(hv[1]);
            va[j * 4 + 2] = bf2f(hv[2]);
            va[j * 4 + 3] = bf2f(hv[3]);
        }

        float s = 0.f;
#pragma unroll
        for (int e = 0; e < 16; ++e) s += va[e];
#pragma unroll
        for (int m = 1; m < 64; m <<= 1) s += __shfl_xor(s, m);
        float tau = (s - 1.f) * (1.f / 1024.f);
        float cprev = 1024.f;

        for (int it = 0; it < 32; ++it) {
            s = 0.f; float c = 0.f;
#pragma unroll
            for (int e = 0; e < 16; ++e) {
                float x = va[e];
                bool mk = x > tau;
                s += mk ? x : 0.f;
                c += mk ? 1.f : 0.f;
            }
#pragma unroll
            for (int m = 1; m < 64; m <<= 1) {
                s += __shfl_xor(s, m);
                c += __shfl_xor(c, m);
            }
            tau = (s - 1.f) / c;
            if (c == cprev) break;
            cprev = c;
        }

        float* ob = out + (size_t)(r0 + row) * D_OUT + lane * 4;
#pragma unroll
        for (int j = 0; j < 4; ++j) {
            float4 o;
            o.x = fmaxf(va[j * 4 + 0] + tau, 0.f);
            o.y = fmaxf(va[j * 4 + 1] + tau, 0.f);
            o.z = fmaxf(va[j * 4 + 2] + tau, 0.f);
            o.w = fmaxf(va[j * 4 + 3] + tau, 0.f);
            *(float4*)(ob + j * 256) = o;
        }
    }
}

extern "C" void kernel_launch(void* const* d_in, const int* in_sizes, int n_in,
                              void* d_out, int out_size, void* d_ws, size_t ws_size,
                              hipStream_t stream) {
    const float* a     = (const float*)d_in[0];
    const float* prior = (const float*)d_in[1];
    const float* gamma = (const float*)d_in[2];
    const float* beta  = (const float*)d_in[3];
    const float* W     = (const float*)d_in[4];
    float* out = (float*)d_out;

    float* ss = (float*)d_ws;                                     // 512 KB @ 0
    unsigned short* Wb = (unsigned short*)((char*)d_ws + 524288); // 256 KB @ 512K
    unsigned short* y  = (unsigned short*)((char*)d_ws + 786432); // 134 MB @ 768K

    const size_t need = 786432 + (size_t)B_ROWS * D_OUT * 2;

    gbn_stats_kernel<<<NCHUNK, VBS, 0, stream>>>(a, gamma, beta, ss);
    wcast_kernel<<<(D_OUT * NA + 255) / 256, 256, 0, stream>>>(W, Wb, D_OUT * NA);

    if (ws_size >= need) {
        gemm_kernel<<<B_ROWS / 16, 256, 0, stream>>>(a, prior, ss, Wb, y);
        sparsemax_kernel<<<B_ROWS / 4, 256, 0, stream>>>(y, out);
    } else {
        fused_kernel<<<B_ROWS / 16, 256, 0, stream>>>(a, prior, ss, Wb, out);
    }
}

// Round 5
// 195.285 us; speedup vs baseline: 1.8024x; 1.8024x over previous
//
#include <hip/hip_runtime.h>
#include <hip/hip_bf16.h>

#define B_ROWS 65536
#define NA 128
#define D_OUT 1024
#define VBS 128
#define NCHUNK (B_ROWS / VBS)   // 512

typedef __attribute__((ext_vector_type(8))) short bf16x8s;
typedef __attribute__((ext_vector_type(4))) float f32x4;
typedef __attribute__((ext_vector_type(4))) unsigned short u16x4;
typedef __attribute__((ext_vector_type(8))) unsigned short u16x8;

static __device__ __forceinline__ short f2bf(float f) {
    unsigned u = __builtin_bit_cast(unsigned, f);
    u = u + 0x7FFFu + ((u >> 16) & 1u);   // round-to-nearest-even to bf16
    return (short)(u >> 16);
}
static __device__ __forceinline__ float bf2f(unsigned short h) {
    unsigned u = ((unsigned)h) << 16;
    return __builtin_bit_cast(float, u);
}

// One block per virtual batch (chunk): 128 threads, one per feature.
__global__ void gbn_stats_kernel(const float* __restrict__ a,
                                 const float* __restrict__ gamma,
                                 const float* __restrict__ beta,
                                 float* __restrict__ ss) {
    int c = blockIdx.x;
    int j = threadIdx.x;            // feature 0..127
    const float* p = a + (size_t)c * (VBS * NA) + j;
    float s = 0.f, s2 = 0.f;
#pragma unroll 8
    for (int r = 0; r < VBS; ++r) {
        float v = p[r * NA];
        s += v; s2 += v * v;
    }
    float mean = s * (1.f / VBS);
    float var  = fmaxf(s2 * (1.f / VBS) - mean * mean, 0.f);   // biased var
    float sc = gamma[j] * rsqrtf(var + 1e-5f);
    float sh = beta[j] - mean * sc;
    float2* o = (float2*)ss + (c * NA + j);
    *o = make_float2(sc, sh);
}

// Pack W (f32 [1024][128]) into bf16 fragment-contiguous chunks:
// chunk c = ((wave*4 + ks)*16 + nf)*64 + lane, lane=(g*16+q), holding
// W[wave*256 + nf*16 + q][ks*32 + g*8 .. +8]. Byte-identical fragment data
// to the previous layout -> numerics unchanged; wave loads become 1KB streams.
__global__ void wpack_kernel(const float* __restrict__ W, u16x8* __restrict__ Wp) {
    int c = blockIdx.x * 256 + threadIdx.x;   // 16384 chunks
    int lane = c & 63;
    int nf   = (c >> 6) & 15;
    int ks   = (c >> 10) & 3;
    int wv   = (c >> 12) & 3;
    int g = lane >> 4, q = lane & 15;
    const float* src = W + (size_t)(wv * 256 + nf * 16 + q) * NA + ks * 32 + g * 8;
    u16x8 h;
#pragma unroll
    for (int i = 0; i < 8; ++i) h[i] = (unsigned short)f2bf(src[i]);
    Wp[c] = h;
}

// One block per 16 rows; wave w owns cols [w*256, +256). Swapped-operand MFMA:
// thread (g,q) holds y[r0+q][w*256+nf*16+4g+r]. launch_bounds(256,2) -> up to
// 256 unified regs: prior prefetched to registers, deep VMEM batching.
__global__ __launch_bounds__(256, 2) void fused_kernel(
    const float* __restrict__ a,
    const float* __restrict__ prior,
    const float* __restrict__ ss,
    const u16x8* __restrict__ Wp,
    float* __restrict__ out) {

    const int tid  = threadIdx.x;
    const int wave = tid >> 6;        // 0..3  (N block of 256)
    const int lane = tid & 63;
    const int g    = lane >> 4;       // 0..3
    const int q    = lane & 15;       // output row within tile

    const int r0    = blockIdx.x * 16;
    const int chunk = r0 >> 7;

    // ---- prefetch prior into registers (HBM latency overlaps GEMM) ----
    float4 pr[16];
    {
        const float* pb = prior + (size_t)(r0 + q) * D_OUT + wave * 256 + 4 * g;
#pragma unroll
        for (int nf = 0; nf < 16; ++nf) pr[nf] = *(const float4*)(pb + nf * 16);
    }

    f32x4 acc[16];
#pragma unroll
    for (int i = 0; i < 16; ++i) acc[i] = (f32x4){0.f, 0.f, 0.f, 0.f};

    const float* ssb = ss + (size_t)chunk * NA * 2;

    // ---- GEMM: y[16 x 1024] = GBN(a_tile)[16 x 128] * W^T (operands swapped) ----
#pragma unroll
    for (int ks = 0; ks < 4; ++ks) {
        const int k0 = ks * 32 + g * 8;
        const float4* ap = (const float4*)(a + (size_t)(r0 + q) * NA + k0);
        float4 v0 = ap[0], v1 = ap[1];
        const float4* sp = (const float4*)(ssb + k0 * 2);   // interleaved (sc,sh)
        float4 s0 = sp[0], s1 = sp[1], s2 = sp[2], s3 = sp[3];
        bf16x8s af;
        af[0] = f2bf(v0.x * s0.x + s0.y);
        af[1] = f2bf(v0.y * s0.z + s0.w);
        af[2] = f2bf(v0.z * s1.x + s1.y);
        af[3] = f2bf(v0.w * s1.z + s1.w);
        af[4] = f2bf(v1.x * s2.x + s2.y);
        af[5] = f2bf(v1.y * s2.z + s2.w);
        af[6] = f2bf(v1.z * s3.x + s3.y);
        af[7] = f2bf(v1.w * s3.z + s3.w);

        const bf16x8s* wp = (const bf16x8s*)(Wp + ((size_t)(wave * 4 + ks) * 16) * 64 + lane);
#pragma unroll
        for (int nf = 0; nf < 16; ++nf) {
            bf16x8s bf = wp[nf * 64];
            acc[nf] = __builtin_amdgcn_mfma_f32_16x16x32_bf16(bf, af, acc[nf], 0, 0, 0);
        }
    }

    // ---- multiply by prior (from registers) ----
#pragma unroll
    for (int nf = 0; nf < 16; ++nf) {
        acc[nf][0] *= pr[nf].x; acc[nf][1] *= pr[nf].y;
        acc[nf][2] *= pr[nf].z; acc[nf][3] *= pr[nf].w;
    }

    // ---- transpose through LDS (bf16): row q owns each thread's 64 values ----
    __shared__ unsigned short ls[16][1032];   // 1032 = 1024 + 8 pad, 33 KB
#pragma unroll
    for (int nf = 0; nf < 16; ++nf) {
        u16x4 h;
        h[0] = (unsigned short)f2bf(acc[nf][0]);
        h[1] = (unsigned short)f2bf(acc[nf][1]);
        h[2] = (unsigned short)f2bf(acc[nf][2]);
        h[3] = (unsigned short)f2bf(acc[nf][3]);
        *(u16x4*)&ls[q][wave * 256 + nf * 16 + 4 * g] = h;
    }
    __syncthreads();

    // ---- per-wave sequential row processing: 16 f32/lane, full-wave Michelot ----
#pragma unroll 1
    for (int rr = 0; rr < 4; ++rr) {
        const int row = wave * 4 + rr;
        float va[16];
#pragma unroll
        for (int j = 0; j < 4; ++j) {
            u16x4 hv = *(const u16x4*)&ls[row][j * 256 + lane * 4];
            va[j * 4 + 0] = bf2f(hv[0]);
            va[j * 4 + 1] = bf2f(hv[1]);
            va[j * 4 + 2] = bf2f(hv[2]);
            va[j * 4 + 3] = bf2f(hv[3]);
        }

        // iteration 1 hoisted: tau = (sum_all - 1)/1024
        float s = 0.f;
#pragma unroll
        for (int e = 0; e < 16; ++e) s += va[e];
#pragma unroll
        for (int m = 1; m < 64; m <<= 1) s += __shfl_xor(s, m);
        float tau = (s - 1.f) * (1.f / 1024.f);
        float cprev = 1024.f;

        for (int it = 0; it < 32; ++it) {
            s = 0.f; float c = 0.f;
#pragma unroll
            for (int e = 0; e < 16; ++e) {
                float x = va[e];
                bool mk = x > tau;
                s += mk ? x : 0.f;
                c += mk ? 1.f : 0.f;
            }
#pragma unroll
            for (int m = 1; m < 64; m <<= 1) {
                s += __shfl_xor(s, m);
                c += __shfl_xor(c, m);
            }
            tau = (s - 1.f) / c;
            if (c == cprev) break;
            cprev = c;
        }

        // ---- output: relu(v + tau), coalesced float4 stores ----
        float* ob = out + (size_t)(r0 + row) * D_OUT + lane * 4;
#pragma unroll
        for (int j = 0; j < 4; ++j) {
            float4 o;
            o.x = fmaxf(va[j * 4 + 0] + tau, 0.f);
            o.y = fmaxf(va[j * 4 + 1] + tau, 0.f);
            o.z = fmaxf(va[j * 4 + 2] + tau, 0.f);
            o.w = fmaxf(va[j * 4 + 3] + tau, 0.f);
            *(float4*)(ob + j * 256) = o;
        }
    }
}

extern "C" void kernel_launch(void* const* d_in, const int* in_sizes, int n_in,
                              void* d_out, int out_size, void* d_ws, size_t ws_size,
                              hipStream_t stream) {
    const float* a     = (const float*)d_in[0];
    const float* prior = (const float*)d_in[1];
    const float* gamma = (const float*)d_in[2];
    const float* beta  = (const float*)d_in[3];
    const float* W     = (const float*)d_in[4];
    float* out = (float*)d_out;

    float* ss = (float*)d_ws;                            // 512 KB @ 0
    u16x8* Wp = (u16x8*)((char*)d_ws + 524288);          // 256 KB @ 512K

    gbn_stats_kernel<<<NCHUNK, VBS, 0, stream>>>(a, gamma, beta, ss);
    wpack_kernel<<<64, 256, 0, stream>>>(W, Wp);
    fused_kernel<<<B_ROWS / 16, 256, 0, stream>>>(a, prior, ss, Wp, out);
}

// Round 6
// 175.049 us; speedup vs baseline: 2.0108x; 1.1156x over previous
//
#include <hip/hip_runtime.h>
#include <hip/hip_bf16.h>

#define B_ROWS 65536
#define NA 128
#define D_OUT 1024
#define VBS 128
#define NCHUNK (B_ROWS / VBS)   // 512

typedef __attribute__((ext_vector_type(8))) short bf16x8s;
typedef __attribute__((ext_vector_type(4))) float f32x4;
typedef __attribute__((ext_vector_type(4))) unsigned short u16x4;
typedef __attribute__((ext_vector_type(8))) unsigned short u16x8;

static __device__ __forceinline__ short f2bf(float f) {
    unsigned u = __builtin_bit_cast(unsigned, f);
    u = u + 0x7FFFu + ((u >> 16) & 1u);   // round-to-nearest-even to bf16
    return (short)(u >> 16);
}
static __device__ __forceinline__ float bf2f(unsigned short h) {
    unsigned u = ((unsigned)h) << 16;
    return __builtin_bit_cast(float, u);
}

// One block per virtual batch (chunk): 128 threads, one per feature.
__global__ void gbn_stats_kernel(const float* __restrict__ a,
                                 const float* __restrict__ gamma,
                                 const float* __restrict__ beta,
                                 float* __restrict__ ss) {
    int c = blockIdx.x;
    int j = threadIdx.x;            // feature 0..127
    const float* p = a + (size_t)c * (VBS * NA) + j;
    float s = 0.f, s2 = 0.f;
#pragma unroll 8
    for (int r = 0; r < VBS; ++r) {
        float v = p[r * NA];
        s += v; s2 += v * v;
    }
    float mean = s * (1.f / VBS);
    float var  = fmaxf(s2 * (1.f / VBS) - mean * mean, 0.f);   // biased var
    float sc = gamma[j] * rsqrtf(var + 1e-5f);
    float sh = beta[j] - mean * sc;
    float2* o = (float2*)ss + (c * NA + j);
    *o = make_float2(sc, sh);
}

// Pack W (f32 [1024][128]) into bf16 fragment-contiguous chunks:
// chunk c = ((wave*4 + ks)*16 + nf)*64 + lane, lane=(g*16+q), holding
// W[wave*256 + nf*16 + q][ks*32 + g*8 .. +8].
__global__ void wpack_kernel(const float* __restrict__ W, u16x8* __restrict__ Wp) {
    int c = blockIdx.x * 256 + threadIdx.x;   // 16384 chunks
    int lane = c & 63;
    int nf   = (c >> 6) & 15;
    int ks   = (c >> 10) & 3;
    int wv   = (c >> 12) & 3;
    int g = lane >> 4, q = lane & 15;
    const float* src = W + (size_t)(wv * 256 + nf * 16 + q) * NA + ks * 32 + g * 8;
    u16x8 h;
#pragma unroll
    for (int i = 0; i < 8; ++i) h[i] = (unsigned short)f2bf(src[i]);
    Wp[c] = h;
}

// One block per 16 rows; wave w owns cols [w*256, +256). Swapped-operand MFMA:
// thread (g,q) holds y[r0+q][w*256+nf*16+4g+r]. Epilogue: *prior (registers),
// bf16 LDS transpose, then 4-row-INTERLEAVED Michelot: sum scan in fmax form
// (VALU), count via ballot+popcount (SALU, no shuffle), S-only shfl reduce.
__global__ __launch_bounds__(256, 2) void fused_kernel(
    const float* __restrict__ a,
    const float* __restrict__ prior,
    const float* __restrict__ ss,
    const u16x8* __restrict__ Wp,
    float* __restrict__ out) {

    const int tid  = threadIdx.x;
    const int wave = tid >> 6;        // 0..3  (N block of 256)
    const int lane = tid & 63;
    const int g    = lane >> 4;       // 0..3
    const int q    = lane & 15;       // output row within tile

    const int r0    = blockIdx.x * 16;
    const int chunk = r0 >> 7;

    // ---- prefetch prior into registers (HBM latency overlaps GEMM) ----
    float4 pr[16];
    {
        const float* pb = prior + (size_t)(r0 + q) * D_OUT + wave * 256 + 4 * g;
#pragma unroll
        for (int nf = 0; nf < 16; ++nf) pr[nf] = *(const float4*)(pb + nf * 16);
    }

    f32x4 acc[16];
#pragma unroll
    for (int i = 0; i < 16; ++i) acc[i] = (f32x4){0.f, 0.f, 0.f, 0.f};

    const float* ssb = ss + (size_t)chunk * NA * 2;

    // ---- GEMM: y[16 x 1024] = GBN(a_tile)[16 x 128] * W^T (operands swapped) ----
#pragma unroll
    for (int ks = 0; ks < 4; ++ks) {
        const int k0 = ks * 32 + g * 8;
        const float4* ap = (const float4*)(a + (size_t)(r0 + q) * NA + k0);
        float4 v0 = ap[0], v1 = ap[1];
        const float4* sp = (const float4*)(ssb + k0 * 2);   // interleaved (sc,sh)
        float4 s0 = sp[0], s1 = sp[1], s2 = sp[2], s3 = sp[3];
        bf16x8s af;
        af[0] = f2bf(v0.x * s0.x + s0.y);
        af[1] = f2bf(v0.y * s0.z + s0.w);
        af[2] = f2bf(v0.z * s1.x + s1.y);
        af[3] = f2bf(v0.w * s1.z + s1.w);
        af[4] = f2bf(v1.x * s2.x + s2.y);
        af[5] = f2bf(v1.y * s2.z + s2.w);
        af[6] = f2bf(v1.z * s3.x + s3.y);
        af[7] = f2bf(v1.w * s3.z + s3.w);

        const bf16x8s* wp = (const bf16x8s*)(Wp + ((size_t)(wave * 4 + ks) * 16) * 64 + lane);
#pragma unroll
        for (int nf = 0; nf < 16; ++nf) {
            bf16x8s bf = wp[nf * 64];
            acc[nf] = __builtin_amdgcn_mfma_f32_16x16x32_bf16(bf, af, acc[nf], 0, 0, 0);
        }
    }

    // ---- multiply by prior (from registers) ----
#pragma unroll
    for (int nf = 0; nf < 16; ++nf) {
        acc[nf][0] *= pr[nf].x; acc[nf][1] *= pr[nf].y;
        acc[nf][2] *= pr[nf].z; acc[nf][3] *= pr[nf].w;
    }

    // ---- transpose through LDS (bf16): row q owns each thread's 64 values ----
    __shared__ unsigned short ls[16][1032];   // 1032 = 1024 + 8 pad, 33 KB
#pragma unroll
    for (int nf = 0; nf < 16; ++nf) {
        u16x4 h;
        h[0] = (unsigned short)f2bf(acc[nf][0]);
        h[1] = (unsigned short)f2bf(acc[nf][1]);
        h[2] = (unsigned short)f2bf(acc[nf][2]);
        h[3] = (unsigned short)f2bf(acc[nf][3]);
        *(u16x4*)&ls[q][wave * 256 + nf * 16 + 4 * g] = h;
    }
    __syncthreads();

    // ---- load this wave's 4 rows: va[4][16], all static indices ----
    float va[4][16];
#pragma unroll
    for (int r = 0; r < 4; ++r) {
        const int row = wave * 4 + r;
#pragma unroll
        for (int j = 0; j < 4; ++j) {
            u16x4 hv = *(const u16x4*)&ls[row][j * 256 + lane * 4];
            va[r][j * 4 + 0] = bf2f(hv[0]);
            va[r][j * 4 + 1] = bf2f(hv[1]);
            va[r][j * 4 + 2] = bf2f(hv[2]);
            va[r][j * 4 + 3] = bf2f(hv[3]);
        }
    }

    // ---- init: tau_0 = (sum_all - 1)/1024 (per row, interleaved reduces) ----
    float tau[4];
    int   cp[4];
    {
        float s[4];
#pragma unroll
        for (int r = 0; r < 4; ++r) {
            float t = 0.f;
#pragma unroll
            for (int e = 0; e < 16; ++e) t += va[r][e];
            s[r] = t;
        }
#pragma unroll
        for (int m = 1; m < 64; m <<= 1) {
#pragma unroll
            for (int r = 0; r < 4; ++r) s[r] += __shfl_xor(s[r], m);
        }
#pragma unroll
        for (int r = 0; r < 4; ++r) {
            tau[r] = (s[r] - 1.f) * (1.f / 1024.f);
            cp[r]  = 1024;
        }
    }

    // ---- Michelot, 4 rows interleaved: tau += (F(tau)-1)/C ----
#pragma unroll 1
    for (int it = 0; it < 32; ++it) {
        float S[4];
        int   C[4];
#pragma unroll
        for (int r = 0; r < 4; ++r) {
            float s1 = 0.f;
            int   c  = 0;
#pragma unroll
            for (int e = 0; e < 16; ++e) {
                float d = va[r][e] - tau[r];
                s1 += fmaxf(d, 0.f);
                c  += (int)__popcll(__ballot(d > 0.f));   // SALU count, wave-uniform
            }
            S[r] = s1; C[r] = c;
        }
        // S-only shuffle reduce, 4 chains interleaved
#pragma unroll
        for (int m = 1; m < 64; m <<= 1) {
#pragma unroll
            for (int r = 0; r < 4; ++r) S[r] += __shfl_xor(S[r], m);
        }
        bool all_done = true;
#pragma unroll
        for (int r = 0; r < 4; ++r) {
            tau[r] += (S[r] - 1.f) * __builtin_amdgcn_rcpf((float)C[r]);
            all_done = all_done && (C[r] == cp[r]);
            cp[r] = C[r];
        }
        if (all_done) break;
    }

    // ---- output: relu(v + tau), coalesced float4 stores ----
#pragma unroll
    for (int r = 0; r < 4; ++r) {
        const int row = wave * 4 + r;
        float* ob = out + (size_t)(r0 + row) * D_OUT + lane * 4;
#pragma unroll
        for (int j = 0; j < 4; ++j) {
            float4 o;
            o.x = fmaxf(va[r][j * 4 + 0] + tau[r], 0.f);
            o.y = fmaxf(va[r][j * 4 + 1] + tau[r], 0.f);
            o.z = fmaxf(va[r][j * 4 + 2] + tau[r], 0.f);
            o.w = fmaxf(va[r][j * 4 + 3] + tau[r], 0.f);
            *(float4*)(ob + j * 256) = o;
        }
    }
}

extern "C" void kernel_launch(void* const* d_in, const int* in_sizes, int n_in,
                              void* d_out, int out_size, void* d_ws, size_t ws_size,
                              hipStream_t stream) {
    const float* a     = (const float*)d_in[0];
    const float* prior = (const float*)d_in[1];
    const float* gamma = (const float*)d_in[2];
    const float* beta  = (const float*)d_in[3];
    const float* W     = (const float*)d_in[4];
    float* out = (float*)d_out;

    float* ss = (float*)d_ws;                            // 512 KB @ 0
    u16x8* Wp = (u16x8*)((char*)d_ws + 524288);          // 256 KB @ 512K

    gbn_stats_kernel<<<NCHUNK, VBS, 0, stream>>>(a, gamma, beta, ss);
    wpack_kernel<<<64, 256, 0, stream>>>(W, Wp);
    fused_kernel<<<B_ROWS / 16, 256, 0, stream>>>(a, prior, ss, Wp, out);
}